// Round 11
// baseline (359.851 us; speedup 1.0000x reference)
//
#include <hip/hip_runtime.h>
#include <hip/hip_bf16.h>

#define DIM 512
#define BB 8
#define LL 8192
#define ML (BB * LL)  // 65536 rows

typedef __attribute__((ext_vector_type(4))) float f32x4;
typedef __attribute__((ext_vector_type(8))) short short8;

__device__ __forceinline__ void gl_lds16(const __hip_bfloat16* g, __hip_bfloat16* l) {
  __builtin_amdgcn_global_load_lds(
      (const __attribute__((address_space(1))) void*)g,
      (__attribute__((address_space(3))) void*)l, 16, 0, 0);
}

// inline-asm LDS read; ordering owned by us (rule #18)
__device__ __forceinline__ short8 ds_read128(const __hip_bfloat16* p) {
  short8 r;
  asm volatile("ds_read_b128 %0, %1"
               : "=v"(r)
               : "v"((const __attribute__((address_space(3))) void*)p));
  return r;
}

__device__ __forceinline__ unsigned short bf16_bits(float f) {
  __hip_bfloat16 h = __float2bfloat16(f);
  return *reinterpret_cast<unsigned short*>(&h);
}

// Packed tile-major layout: element (r,k) -> tile (r>>7,k>>5) 8KB block,
// internal [row][chunk-pos][8], T2 XOR pre-baked.
__device__ __forceinline__ size_t packA(int r, int k) {
  return ((size_t)((r >> 7) * 16 + (k >> 5))) * 4096 + (r & 127) * 32 +
         (((((k >> 3) & 3) ^ ((r >> 1) & 3))) << 3) + (k & 7);
}

// ---------------- zero the row-sumsq accumulator ----------------------------
__global__ void zero_ss(float* __restrict__ ss) {
  ss[blockIdx.x * 256 + threadIdx.x] = 0.0f;
}

// ---------------- depthwise causal conv (K=4, left pad 3) -> packed bf16 ----
__global__ void conv_cast_kernel(const float* __restrict__ x,
                                 const float* __restrict__ cwt,
                                 const float* __restrict__ cb,
                                 __hip_bfloat16* __restrict__ xc) {
  const int tid = blockIdx.x * 256 + threadIdx.x;
  const int d = (tid & 127) << 2;  // 0..508 step 4
  const int bl = tid >> 7;
  const int l = bl & (LL - 1);
  float4 acc = *(const float4*)(cb + d);
  float4 w[4];
#pragma unroll
  for (int k = 0; k < 4; ++k) w[k] = *(const float4*)(cwt + k * DIM + d);
#pragma unroll
  for (int k = 0; k < 4; ++k) {
    if (l - 3 + k >= 0) {
      const float4 xv = *(const float4*)(x + (size_t)(bl - 3 + k) * DIM + d);
      acc.x += xv.x * w[k].x;
      acc.y += xv.y * w[k].y;
      acc.z += xv.z * w[k].z;
      acc.w += xv.w * w[k].w;
    }
  }
  ushort4 o;
  o.x = bf16_bits(acc.x);
  o.y = bf16_bits(acc.y);
  o.z = bf16_bits(acc.z);
  o.w = bf16_bits(acc.w);
  *(ushort4*)((unsigned short*)xc + packA(bl, d)) = o;
}

// ---------------- weight prep: cast (or transpose-cast) into packed layout --
__global__ void prep_w(const float* __restrict__ src,
                       __hip_bfloat16* __restrict__ dst, int transpose,
                       const float* __restrict__ cw, float* __restrict__ cwt) {
  const int i = blockIdx.x * 256 + threadIdx.x;  // 0..262143
  if (transpose) {
    const int k = i >> 9, n = i & 511;
    dst[packA(n, k)] = __float2bfloat16(src[i]);
  } else {
    const int n = i >> 9, k = i & 511;
    dst[packA(n, k)] = __float2bfloat16(src[i]);
  }
  if (cwt != nullptr && i < DIM * 4) cwt[(i & 3) * DIM + (i >> 2)] = cw[i];
}

// ---------------- GEMM (R10 verbatim) ---------------------------------------
template <int EPI>
__global__ __launch_bounds__(256) void gemm_bt(
    const __hip_bfloat16* __restrict__ A, const __hip_bfloat16* __restrict__ Bt,
    float* __restrict__ Cf, __hip_bfloat16* __restrict__ Cb,
    const __hip_bfloat16* __restrict__ C1, float* __restrict__ ss) {
  __shared__ __hip_bfloat16 sA[3][128 * 32];
  __shared__ __hip_bfloat16 sB[3][128 * 32];
  const int bid = blockIdx.x;
  const int swz = (bid & 7) * (gridDim.x >> 3) + (bid >> 3);
  const int bm = swz >> 2;  // nbn = 4
  const int bn = swz & 3;
  const int tid = threadIdx.x;
  const int wv = tid >> 6, ln = tid & 63;
  const int wr = wv >> 1, wc = wv & 1;
  const int idx = ln & 15, kg = ln >> 4;

  f32x4 acc[4][4] = {};
  const int kgx = ((kg ^ ((idx >> 1) & 3)) << 3);

  const __hip_bfloat16* gA = A + (size_t)bm * 16 * 4096;
  const __hip_bfloat16* gB = Bt + (size_t)bn * 16 * 4096;
  const int e0 = wv * 512;
  const int e1 = 2048 + wv * 512;
  const __hip_bfloat16* gAl = gA + e0 + ln * 8;
  const __hip_bfloat16* gBl = gB + e0 + ln * 8;

  const int nt = 16;

#define STAGE(t, b)                          \
  do {                                       \
    const int o_ = (t) * 4096;               \
    gl_lds16(gAl + o_, &sA[(b)][e0]);        \
    gl_lds16(gAl + o_ + 2048, &sA[(b)][e1]); \
    gl_lds16(gBl + o_, &sB[(b)][e0]);        \
    gl_lds16(gBl + o_ + 2048, &sB[(b)][e1]); \
  } while (0)

  STAGE(0, 0);
  STAGE(1, 1);

  int rb = 0;
  for (int t = 0; t < nt; ++t) {
    if (t + 1 < nt)
      asm volatile("s_waitcnt vmcnt(4)" ::: "memory");
    else
      asm volatile("s_waitcnt vmcnt(0)" ::: "memory");
    asm volatile("s_barrier" ::: "memory");
    if (t + 2 < nt) {
      const int wbuf = rb < 1 ? rb + 2 : rb - 1;
      STAGE(t + 2, wbuf);
    }
    short8 af[4], bfv[4];
#pragma unroll
    for (int mi = 0; mi < 4; ++mi)
      af[mi] = ds_read128(&sA[rb][(wr * 64 + mi * 16 + idx) * 32 + kgx]);
#pragma unroll
    for (int ni = 0; ni < 4; ++ni)
      bfv[ni] = ds_read128(&sB[rb][(wc * 64 + ni * 16 + idx) * 32 + kgx]);
    asm volatile("s_waitcnt lgkmcnt(0)" ::: "memory");
    __builtin_amdgcn_sched_barrier(0);
    __builtin_amdgcn_s_setprio(1);
#pragma unroll
    for (int mi = 0; mi < 4; ++mi)
#pragma unroll
      for (int ni = 0; ni < 4; ++ni)
        acc[mi][ni] = __builtin_amdgcn_mfma_f32_16x16x32_bf16(
            af[mi], bfv[ni], acc[mi][ni], 0, 0, 0);
    __builtin_amdgcn_s_setprio(0);
    rb = rb == 2 ? 0 : rb + 1;
  }
#undef STAGE

  const int cr0 = bm * 128 + wr * 64;
  const int cc0 = bn * 128 + wc * 64;
#pragma unroll
  for (int mi = 0; mi < 4; ++mi) {
#pragma unroll
    for (int j = 0; j < 4; ++j) {
      const int r = cr0 + mi * 16 + kg * 4 + j;
      if (EPI == 0) {
        float ps = 0.0f;
#pragma unroll
        for (int ni = 0; ni < 4; ++ni) {
          const float v = acc[mi][ni][j];
          ps += v * v;
          Cb[packA(r, cc0 + ni * 16 + idx)] = __float2bfloat16(v);
        }
        ps += __shfl_xor(ps, 1, 64);
        ps += __shfl_xor(ps, 2, 64);
        ps += __shfl_xor(ps, 4, 64);
        ps += __shfl_xor(ps, 8, 64);
        if (idx == 0) atomicAdd(ss + r, ps);
      } else {
        const float sc = 1.0f / fmaxf(sqrtf(ss[r]), 1e-12f);
#pragma unroll
        for (int ni = 0; ni < 4; ++ni) {
          const int c = cc0 + ni * 16 + idx;
          if (EPI == 1) {
            const float v = acc[mi][ni][j] * sc;
            const float ge =
                0.5f * v * (1.0f + erff(v * 0.70710678118654752f));
            Cb[packA(r, c)] = __float2bfloat16(ge);
          } else {
            Cf[(size_t)r * DIM + c] =
                acc[mi][ni][j] + sc * __bfloat162float(C1[packA(r, c)]);
          }
        }
      }
    }
  }
}

// ---------------- DIAGNOSTIC 1: staging+sync loop only ----------------------
__global__ __launch_bounds__(256) void diag_stage(
    const __hip_bfloat16* __restrict__ A, const __hip_bfloat16* __restrict__ Bt,
    float* __restrict__ dump) {
  __shared__ __hip_bfloat16 sA[3][128 * 32];
  __shared__ __hip_bfloat16 sB[3][128 * 32];
  const int bid = blockIdx.x;
  const int swz = (bid & 7) * (gridDim.x >> 3) + (bid >> 3);
  const int bm = swz >> 2;
  const int bn = swz & 3;
  const int tid = threadIdx.x;
  const int wv = tid >> 6, ln = tid & 63;
  const __hip_bfloat16* gA = A + (size_t)bm * 16 * 4096;
  const __hip_bfloat16* gB = Bt + (size_t)bn * 16 * 4096;
  const int e0 = wv * 512;
  const int e1 = 2048 + wv * 512;
  const __hip_bfloat16* gAl = gA + e0 + ln * 8;
  const __hip_bfloat16* gBl = gB + e0 + ln * 8;
  const int nt = 16;
#define STAGE(t, b)                          \
  do {                                       \
    const int o_ = (t) * 4096;               \
    gl_lds16(gAl + o_, &sA[(b)][e0]);        \
    gl_lds16(gAl + o_ + 2048, &sA[(b)][e1]); \
    gl_lds16(gBl + o_, &sB[(b)][e0]);        \
    gl_lds16(gBl + o_ + 2048, &sB[(b)][e1]); \
  } while (0)
  STAGE(0, 0);
  STAGE(1, 1);
  int rb = 0;
  for (int t = 0; t < nt; ++t) {
    if (t + 1 < nt)
      asm volatile("s_waitcnt vmcnt(4)" ::: "memory");
    else
      asm volatile("s_waitcnt vmcnt(0)" ::: "memory");
    asm volatile("s_barrier" ::: "memory");
    if (t + 2 < nt) {
      const int wbuf = rb < 1 ? rb + 2 : rb - 1;
      STAGE(t + 2, wbuf);
    }
    rb = rb == 2 ? 0 : rb + 1;
  }
#undef STAGE
  // guard: consume staged data so nothing can be elided
  dump[(size_t)bid * 256 + tid] =
      __bfloat162float(sA[0][tid]) + __bfloat162float(sB[0][tid]);
}

// ---------------- DIAGNOSTIC 2: full loop, near-free epilogue ---------------
__global__ __launch_bounds__(256) void diag_noepi(
    const __hip_bfloat16* __restrict__ A, const __hip_bfloat16* __restrict__ Bt,
    float* __restrict__ dump) {
  __shared__ __hip_bfloat16 sA[3][128 * 32];
  __shared__ __hip_bfloat16 sB[3][128 * 32];
  const int bid = blockIdx.x;
  const int swz = (bid & 7) * (gridDim.x >> 3) + (bid >> 3);
  const int bm = swz >> 2;
  const int bn = swz & 3;
  const int tid = threadIdx.x;
  const int wv = tid >> 6, ln = tid & 63;
  const int wr = wv >> 1, wc = wv & 1;
  const int idx = ln & 15, kg = ln >> 4;
  f32x4 acc[4][4] = {};
  const int kgx = ((kg ^ ((idx >> 1) & 3)) << 3);
  const __hip_bfloat16* gA = A + (size_t)bm * 16 * 4096;
  const __hip_bfloat16* gB = Bt + (size_t)bn * 16 * 4096;
  const int e0 = wv * 512;
  const int e1 = 2048 + wv * 512;
  const __hip_bfloat16* gAl = gA + e0 + ln * 8;
  const __hip_bfloat16* gBl = gB + e0 + ln * 8;
  const int nt = 16;
#define STAGE(t, b)                          \
  do {                                       \
    const int o_ = (t) * 4096;               \
    gl_lds16(gAl + o_, &sA[(b)][e0]);        \
    gl_lds16(gAl + o_ + 2048, &sA[(b)][e1]); \
    gl_lds16(gBl + o_, &sB[(b)][e0]);        \
    gl_lds16(gBl + o_ + 2048, &sB[(b)][e1]); \
  } while (0)
  STAGE(0, 0);
  STAGE(1, 1);
  int rb = 0;
  for (int t = 0; t < nt; ++t) {
    if (t + 1 < nt)
      asm volatile("s_waitcnt vmcnt(4)" ::: "memory");
    else
      asm volatile("s_waitcnt vmcnt(0)" ::: "memory");
    asm volatile("s_barrier" ::: "memory");
    if (t + 2 < nt) {
      const int wbuf = rb < 1 ? rb + 2 : rb - 1;
      STAGE(t + 2, wbuf);
    }
    short8 af[4], bfv[4];
#pragma unroll
    for (int mi = 0; mi < 4; ++mi)
      af[mi] = ds_read128(&sA[rb][(wr * 64 + mi * 16 + idx) * 32 + kgx]);
#pragma unroll
    for (int ni = 0; ni < 4; ++ni)
      bfv[ni] = ds_read128(&sB[rb][(wc * 64 + ni * 16 + idx) * 32 + kgx]);
    asm volatile("s_waitcnt lgkmcnt(0)" ::: "memory");
    __builtin_amdgcn_sched_barrier(0);
    __builtin_amdgcn_s_setprio(1);
#pragma unroll
    for (int mi = 0; mi < 4; ++mi)
#pragma unroll
      for (int ni = 0; ni < 4; ++ni)
        acc[mi][ni] = __builtin_amdgcn_mfma_f32_16x16x32_bf16(
            af[mi], bfv[ni], acc[mi][ni], 0, 0, 0);
    __builtin_amdgcn_s_setprio(0);
    rb = rb == 2 ? 0 : rb + 1;
  }
#undef STAGE
  // near-free epilogue: sum all 16 accumulators (keeps every MFMA live,
  // rule #17) -> one f32x4 store per thread
  f32x4 tot = acc[0][0];
#pragma unroll
  for (int mi = 0; mi < 4; ++mi)
#pragma unroll
    for (int ni = 0; ni < 4; ++ni)
      if (mi + ni) tot += acc[mi][ni];
  *(f32x4*)(dump + 4194304 + ((size_t)bid * 256 + tid) * 4) = tot;
}

extern "C" void kernel_launch(void* const* d_in, const int* in_sizes, int n_in,
                              void* d_out, int out_size, void* d_ws,
                              size_t ws_size, hipStream_t stream) {
  const float* x = (const float*)d_in[0];
  const float* cw = (const float*)d_in[1];
  const float* cb = (const float*)d_in[2];
  const float* qw = (const float*)d_in[3];
  const float* w1 = (const float*)d_in[4];
  const float* w2 = (const float*)d_in[5];
  float* out = (float*)d_out;

  char* ws = (char*)d_ws;
  __hip_bfloat16* xconv = (__hip_bfloat16*)ws;
  __hip_bfloat16* C1 = (__hip_bfloat16*)(ws + (size_t)67108864);
  __hip_bfloat16* wA = (__hip_bfloat16*)(ws + (size_t)134217728);
  __hip_bfloat16* wB = wA + DIM * DIM;
  float* cwt = (float*)(ws + (size_t)134217728 + 1048576);
  float* ss = (float*)(ws + (size_t)134217728 + 1048576 + 8192);
  __hip_bfloat16* g = xconv;  // alias: x_conv dead after GEMM1

  const int gemm_grid = (ML / 128) * (DIM / 128);  // 2048

  zero_ss<<<ML / 256, 256, 0, stream>>>(ss);
  prep_w<<<DIM * DIM / 256, 256, 0, stream>>>(qw, wA, 0, cw, cwt);
  prep_w<<<DIM * DIM / 256, 256, 0, stream>>>(w1, wB, 1, nullptr, nullptr);
  conv_cast_kernel<<<ML * (DIM / 4) / 256, 256, 0, stream>>>(x, cwt, cb, xconv);
  // GEMM1: C1 = x_conv @ q_w^T (packed bf16) + row sumsq -> ss
  gemm_bt<0><<<gemm_grid, 256, 0, stream>>>(xconv, wA, nullptr, C1, nullptr,
                                            ss);
  // ---- diagnostics (write into d_out, fully overwritten by GEMM3 later) ----
  diag_stage<<<gemm_grid, 256, 0, stream>>>(xconv, wA, out);
  diag_noepi<<<gemm_grid, 256, 0, stream>>>(xconv, wA, out);
  // --------------------------------------------------------------------------
  prep_w<<<DIM * DIM / 256, 256, 0, stream>>>(w2, wA, 1, nullptr, nullptr);
  // GEMM2: g = gelu(sc * (C1 @ w1)) -> packed bf16
  gemm_bt<1><<<gemm_grid, 256, 0, stream>>>(C1, wB, nullptr, g, nullptr, ss);
  // GEMM3: out = sc*C1 + g @ w2 -> f32 row-major
  gemm_bt<2><<<gemm_grid, 256, 0, stream>>>(g, wA, out, nullptr, C1, ss);
}

// Round 14
// 320.753 us; speedup vs baseline: 1.1219x; 1.1219x over previous
//
#include <hip/hip_runtime.h>
#include <hip/hip_bf16.h>

#define DIM 512
#define BB 8
#define LL 8192
#define ML (BB * LL)  // 65536 rows

typedef __attribute__((ext_vector_type(4))) float f32x4;
typedef __attribute__((ext_vector_type(8))) short short8;

__device__ __forceinline__ unsigned short bf16_bits(float f) {
  __hip_bfloat16 h = __float2bfloat16(f);
  return *reinterpret_cast<unsigned short*>(&h);
}

// Packed tile-major layout: element (r,k) of a [rows][512] bf16 matrix lives
// in 8KB tile (r>>7, k>>5); internal offset (r&127)*32 + chunkpos*8 + (k&7),
// chunkpos = ((k>>3)&3) ^ ((r>>1)&3)  (T2 XOR pre-baked).
// A wave's MFMA fragment (16 rows x 32 k) is a CONTIGUOUS 1KB block here ->
// direct global fragment loads are perfectly coalesced (R9's failure fixed).
__device__ __forceinline__ size_t packA(int r, int k) {
  return ((size_t)((r >> 7) * 16 + (k >> 5))) * 4096 + (r & 127) * 32 +
         (((((k >> 3) & 3) ^ ((r >> 1) & 3))) << 3) + (k & 7);
}

// ---------------- zero the row-sumsq accumulator ----------------------------
__global__ void zero_ss(float* __restrict__ ss) {
  ss[blockIdx.x * 256 + threadIdx.x] = 0.0f;
}

// ---------------- depthwise causal conv (K=4, left pad 3) -> packed bf16 ----
__global__ void conv_cast_kernel(const float* __restrict__ x,
                                 const float* __restrict__ cwt,
                                 const float* __restrict__ cb,
                                 __hip_bfloat16* __restrict__ xc) {
  const int tid = blockIdx.x * 256 + threadIdx.x;
  const int d = (tid & 127) << 2;  // 0..508 step 4
  const int bl = tid >> 7;
  const int l = bl & (LL - 1);
  float4 acc = *(const float4*)(cb + d);
  float4 w[4];
#pragma unroll
  for (int k = 0; k < 4; ++k) w[k] = *(const float4*)(cwt + k * DIM + d);
#pragma unroll
  for (int k = 0; k < 4; ++k) {
    if (l - 3 + k >= 0) {
      const float4 xv = *(const float4*)(x + (size_t)(bl - 3 + k) * DIM + d);
      acc.x += xv.x * w[k].x;
      acc.y += xv.y * w[k].y;
      acc.z += xv.z * w[k].z;
      acc.w += xv.w * w[k].w;
    }
  }
  ushort4 o;
  o.x = bf16_bits(acc.x);
  o.y = bf16_bits(acc.y);
  o.z = bf16_bits(acc.z);
  o.w = bf16_bits(acc.w);
  *(ushort4*)((unsigned short*)xc + packA(bl, d)) = o;
}

// ---------------- weight prep: cast (or transpose-cast) into packed layout --
__global__ void prep_w(const float* __restrict__ src,
                       __hip_bfloat16* __restrict__ dst, int transpose,
                       const float* __restrict__ cw, float* __restrict__ cwt) {
  const int i = blockIdx.x * 256 + threadIdx.x;  // 0..262143
  if (transpose) {
    const int k = i >> 9, n = i & 511;
    dst[packA(n, k)] = __float2bfloat16(src[i]);
  } else {
    const int n = i >> 9, k = i & 511;
    dst[packA(n, k)] = __float2bfloat16(src[i]);
  }
  if (cwt != nullptr && i < DIM * 4) cwt[(i & 3) * DIM + (i >> 2)] = cw[i];
}

// ---------------- GEMM: C[M,512] = A(packed) @ Bt(packed)^T -----------------
// NO LDS, NO barriers, NO waitcnt asm. Each wave owns a 64x64 output tile;
// per K-tile: 8 contiguous-1KB fragment loads -> 16 MFMA. Register
// double-buffer with NAMED even/odd frag sets (rule #20). 4 waves stacked on
// M share the B strip (L1 broadcast). T1 XCD chunking: one bm's 8 bn-blocks
// on one XCD -> A tile served once from HBM, B fully L2-resident.
// EPI 0: write C1 packed bf16 + per-row sumsq atomics into ss
// EPI 1: v *= 1/max(sqrt(ss[r]),eps); exact GELU -> packed bf16
// EPI 2: out(row-major f32) = v + sc * C1_packed[r,c]
template <int EPI>
__global__ __launch_bounds__(256) void gemm_direct(
    const __hip_bfloat16* __restrict__ A, const __hip_bfloat16* __restrict__ Bt,
    float* __restrict__ Cf, __hip_bfloat16* __restrict__ Cb,
    const __hip_bfloat16* __restrict__ C1, float* __restrict__ ss) {
  // T1: XCD-chunked swizzle; grid = 2048 (%8==0)
  const int bid = blockIdx.x;
  const int swz = (bid & 7) * (gridDim.x >> 3) + (bid >> 3);
  const int bm = swz >> 3;  // nbn = 512/64 = 8
  const int bn = swz & 7;
  const int tid = threadIdx.x;
  const int wv = tid >> 6, ln = tid & 63;
  const int idx = ln & 15, kg = ln >> 4;

  f32x4 acc[4][4] = {};

  // fragment read offset inside a packed tile (same math as the LDS path):
  const int kgx = ((kg ^ ((idx >> 1) & 3)) << 3);

  // A: wave's rows bm*256 + wv*64 .. +64 -> packed row-block bm*2 + (wv>>1),
  //    in-tile row base (wv&1)*64.
  const __hip_bfloat16* tA =
      A + (size_t)(bm * 2 + (wv >> 1)) * 16 * 4096 + ((wv & 1) * 64) * 32;
  // B: rows bn*64 .. +64 -> row-block bn>>1, in-tile row base (bn&1)*64.
  const __hip_bfloat16* tB =
      Bt + (size_t)(bn >> 1) * 16 * 4096 + ((bn & 1) * 64) * 32;

#define LOADF(t, af, bf)                                                    \
  do {                                                                      \
    const int o_ = (t) * 4096;                                              \
    _Pragma("unroll") for (int mi = 0; mi < 4; ++mi) af[mi] =               \
        *(const short8*)(tA + o_ + (mi * 16 + idx) * 32 + kgx);             \
    _Pragma("unroll") for (int ni = 0; ni < 4; ++ni) bf[ni] =               \
        *(const short8*)(tB + o_ + (ni * 16 + idx) * 32 + kgx);             \
  } while (0)

#define MFMAS(af, bf)                                                  \
  do {                                                                 \
    _Pragma("unroll") for (int mi = 0; mi < 4; ++mi)                   \
        _Pragma("unroll") for (int ni = 0; ni < 4; ++ni) acc[mi][ni] = \
            __builtin_amdgcn_mfma_f32_16x16x32_bf16(af[mi], bf[ni],    \
                                                    acc[mi][ni], 0, 0, 0); \
  } while (0)

  short8 af0[4], bf0[4], af1[4], bf1[4];
  LOADF(0, af0, bf0);
#pragma unroll
  for (int t = 0; t < 16; t += 2) {
    if (t + 1 < 16) LOADF(t + 1, af1, bf1);
    MFMAS(af0, bf0);
    if (t + 2 < 16) LOADF(t + 2, af0, bf0);
    MFMAS(af1, bf1);
  }
#undef LOADF
#undef MFMAS

  // epilogue: C/D layout col = lane&15, row = (lane>>4)*4 + j  [m89-verified]
  const int cr0 = bm * 256 + wv * 64;
  const int cc0 = bn * 64;
#pragma unroll
  for (int mi = 0; mi < 4; ++mi) {
#pragma unroll
    for (int j = 0; j < 4; ++j) {
      const int r = cr0 + mi * 16 + kg * 4 + j;
      if (EPI == 0) {
        float ps = 0.0f;
#pragma unroll
        for (int ni = 0; ni < 4; ++ni) {
          const float v = acc[mi][ni][j];
          ps += v * v;
          Cb[packA(r, cc0 + ni * 16 + idx)] = __float2bfloat16(v);
        }
        ps += __shfl_xor(ps, 1, 64);
        ps += __shfl_xor(ps, 2, 64);
        ps += __shfl_xor(ps, 4, 64);
        ps += __shfl_xor(ps, 8, 64);
        if (idx == 0) atomicAdd(ss + r, ps);
      } else {
        const float sc = 1.0f / fmaxf(sqrtf(ss[r]), 1e-12f);
#pragma unroll
        for (int ni = 0; ni < 4; ++ni) {
          const int c = cc0 + ni * 16 + idx;
          if (EPI == 1) {
            const float v = acc[mi][ni][j] * sc;
            const float ge =
                0.5f * v * (1.0f + erff(v * 0.70710678118654752f));
            Cb[packA(r, c)] = __float2bfloat16(ge);
          } else {
            Cf[(size_t)r * DIM + c] =
                acc[mi][ni][j] + sc * __bfloat162float(C1[packA(r, c)]);
          }
        }
      }
    }
  }
}

extern "C" void kernel_launch(void* const* d_in, const int* in_sizes, int n_in,
                              void* d_out, int out_size, void* d_ws,
                              size_t ws_size, hipStream_t stream) {
  const float* x = (const float*)d_in[0];
  const float* cw = (const float*)d_in[1];
  const float* cb = (const float*)d_in[2];
  const float* qw = (const float*)d_in[3];
  const float* w1 = (const float*)d_in[4];
  const float* w2 = (const float*)d_in[5];
  float* out = (float*)d_out;

  // ws layout (high-water 135.54 MB, under proven-safe 135.79 MB):
  //   [0, 64Mi)        x_conv packed bf16, reused as g after GEMM1
  //   [64Mi, 128Mi)    C1 packed bf16 (lives to GEMM3)
  //   [128Mi, +512K)   weight slot A (packed bf16)
  //   [+512K, +1M)     weight slot B (packed bf16)
  //   [+1M, +1M+8K)    cwt f32 [4][512]
  //   [+1M+8K, +1.25M) ss f32 [ML]
  char* ws = (char*)d_ws;
  __hip_bfloat16* xconv = (__hip_bfloat16*)ws;
  __hip_bfloat16* C1 = (__hip_bfloat16*)(ws + (size_t)67108864);
  __hip_bfloat16* wA = (__hip_bfloat16*)(ws + (size_t)134217728);
  __hip_bfloat16* wB = wA + DIM * DIM;
  float* cwt = (float*)(ws + (size_t)134217728 + 1048576);
  float* ss = (float*)(ws + (size_t)134217728 + 1048576 + 8192);
  __hip_bfloat16* g = xconv;  // alias: x_conv dead after GEMM1

  const int gemm_grid = (ML / 256) * (DIM / 64);  // 2048 (%8==0 for T1)

  zero_ss<<<ML / 256, 256, 0, stream>>>(ss);
  prep_w<<<DIM * DIM / 256, 256, 0, stream>>>(qw, wA, 0, cw, cwt);
  prep_w<<<DIM * DIM / 256, 256, 0, stream>>>(w1, wB, 1, nullptr, nullptr);
  conv_cast_kernel<<<ML * (DIM / 4) / 256, 256, 0, stream>>>(x, cwt, cb, xconv);
  // GEMM1: C1 = x_conv @ q_w^T (packed bf16) + row sumsq -> ss
  gemm_direct<0><<<gemm_grid, 256, 0, stream>>>(xconv, wA, nullptr, C1,
                                                nullptr, ss);
  prep_w<<<DIM * DIM / 256, 256, 0, stream>>>(w2, wA, 1, nullptr, nullptr);
  // GEMM2: g = gelu(sc * (C1 @ w1)) -> packed bf16
  gemm_direct<1><<<gemm_grid, 256, 0, stream>>>(C1, wB, nullptr, g, nullptr,
                                                ss);
  // GEMM3: out = sc*C1 + g @ w2 -> f32 row-major
  gemm_direct<2><<<gemm_grid, 256, 0, stream>>>(g, wA, out, nullptr, C1, ss);
}

// Round 16
// 240.681 us; speedup vs baseline: 1.4951x; 1.3327x over previous
//
#include <hip/hip_runtime.h>
#include <hip/hip_bf16.h>

#define DIM 512
#define BB 8
#define LL 8192
#define ML (BB * LL)  // 65536 rows

typedef __attribute__((ext_vector_type(4))) float f32x4;
typedef __attribute__((ext_vector_type(8))) short short8;

__device__ __forceinline__ void gl_lds16(const __hip_bfloat16* g, __hip_bfloat16* l) {
  __builtin_amdgcn_global_load_lds(
      (const __attribute__((address_space(1))) void*)g,
      (__attribute__((address_space(3))) void*)l, 16, 0, 0);
}

__device__ __forceinline__ unsigned short bf16_bits(float f) {
  __hip_bfloat16 h = __float2bfloat16(f);
  return *reinterpret_cast<unsigned short*>(&h);
}

// Packed tile-major GLOBAL layout (verified R10/R14): element (r,k) ->
// 8KB tile (r>>7, k>>5); offset (r&127)*32 + chunkpos*8 + (k&7),
// chunkpos = ((k>>3)&3) ^ ((r>>1)&3)  (T2 XOR pre-baked).
__device__ __forceinline__ size_t packA(int r, int k) {
  return ((size_t)((r >> 7) * 16 + (k >> 5))) * 4096 + (r & 127) * 32 +
         (((((k >> 3) & 3) ^ ((r >> 1) & 3))) << 3) + (k & 7);
}

// 64-row packed LDS layout (same scheme, half-tile): r in [0,64), k in [0,512)
__device__ __forceinline__ int ldsoff(int r, int c) {
  return (c >> 5) * 2048 + r * 32 +
         (((((c >> 3) & 3) ^ ((r >> 1) & 3))) << 3) + (c & 7);
}

// ---------------- depthwise causal conv (K=4, left pad 3) -> packed bf16 ----
__global__ void conv_cast_kernel(const float* __restrict__ x,
                                 const float* __restrict__ cwt,
                                 const float* __restrict__ cb,
                                 __hip_bfloat16* __restrict__ xc) {
  const int tid = blockIdx.x * 256 + threadIdx.x;
  const int d = (tid & 127) << 2;  // 0..508 step 4
  const int bl = tid >> 7;
  const int l = bl & (LL - 1);
  float4 acc = *(const float4*)(cb + d);
  float4 w[4];
#pragma unroll
  for (int k = 0; k < 4; ++k) w[k] = *(const float4*)(cwt + k * DIM + d);
#pragma unroll
  for (int k = 0; k < 4; ++k) {
    if (l - 3 + k >= 0) {
      const float4 xv = *(const float4*)(x + (size_t)(bl - 3 + k) * DIM + d);
      acc.x += xv.x * w[k].x;
      acc.y += xv.y * w[k].y;
      acc.z += xv.z * w[k].z;
      acc.w += xv.w * w[k].w;
    }
  }
  ushort4 o;
  o.x = bf16_bits(acc.x);
  o.y = bf16_bits(acc.y);
  o.z = bf16_bits(acc.z);
  o.w = bf16_bits(acc.w);
  *(ushort4*)((unsigned short*)xc + packA(bl, d)) = o;
}

// ---------------- weight prep: cast (or transpose-cast) into packed layout --
__global__ void prep_w(const float* __restrict__ src,
                       __hip_bfloat16* __restrict__ dst, int transpose,
                       const float* __restrict__ cw, float* __restrict__ cwt) {
  const int i = blockIdx.x * 256 + threadIdx.x;  // 0..262143
  if (transpose) {
    const int k = i >> 9, n = i & 511;
    dst[packA(n, k)] = __float2bfloat16(src[i]);
  } else {
    const int n = i >> 9, k = i & 511;
    dst[packA(n, k)] = __float2bfloat16(src[i]);
  }
  if (cwt != nullptr && i < DIM * 4) cwt[(i & 3) * DIM + (i >> 2)] = cw[i];
}

// ---------------- FUSED: per 64-row block, GEMM1 -> l2norm -> GEMM2(gelu)
// -> GEMM3(+residual), all intermediates in LDS. HBM: read xconv, write out.
// Weights (3 x 512KB packed bf16) are L2-resident.
// 8 waves; each wave owns all 64 rows x its 64-col strip per GEMM.
__global__ __launch_bounds__(512, 2) void fused_kernel(
    const __hip_bfloat16* __restrict__ xc, const __hip_bfloat16* __restrict__ wq,
    const __hip_bfloat16* __restrict__ w1t,
    const __hip_bfloat16* __restrict__ w2t, float* __restrict__ out) {
  __shared__ __hip_bfloat16 sX[16 * 2048];  // 64KB: xconv, later G
  __shared__ __hip_bfloat16 sC[16 * 2048];  // 64KB: C1 (lives to the end)
  __shared__ float ssL[64];
  const int tid = threadIdx.x;
  const int wv = tid >> 6, ln = tid & 63;
  const int idx = ln & 15, kg = ln >> 4;
  const int r0 = blockIdx.x * 64;
  const int kgx = ((kg ^ ((idx >> 1) & 3)) << 3);  // frag chunk (rows: r%8==idx%8)
  const int cbase = wv * 64;

  if (tid < 64) ssL[tid] = 0.0f;

  // ---- stage xconv rows r0..r0+63 -> sX (16 contiguous 4KB half-chunks) ----
  {
    const __hip_bfloat16* gbase =
        xc + (size_t)(r0 >> 7) * 16 * 4096 + (size_t)(r0 & 64) * 32;
#pragma unroll
    for (int j = 0; j < 8; ++j) {
      const int e0 = wv * 4096 + j * 512;  // 512-elem run, within one chunk
      gl_lds16(gbase + (e0 >> 11) * 4096 + (e0 & 2047) + ln * 8, &sX[e0]);
    }
  }
  __syncthreads();  // drains vmcnt; ssL zero visible

  // per-wave packed-weight tile bases (wave's 64 n-rows)
  const size_t wofs = (size_t)(wv >> 1) * 16 * 4096 + (size_t)((wv & 1) * 64) * 32;
  const __hip_bfloat16* tq = wq + wofs;
  const __hip_bfloat16* t1 = w1t + wofs;
  const __hip_bfloat16* t2 = w2t + wofs;

#define GEMM_LOOP(ASRC_EXPR, BPTR)                                          \
  _Pragma("unroll 2") for (int kt = 0; kt < 16; ++kt) {                     \
    short8 af[4], bf[4];                                                    \
    _Pragma("unroll") for (int mi = 0; mi < 4; ++mi) af[mi] =               \
        *(const short8*)(ASRC_EXPR + kt * 2048 + (mi * 16 + idx) * 32 + kgx); \
    _Pragma("unroll") for (int ni = 0; ni < 4; ++ni) bf[ni] =               \
        *(const short8*)(BPTR + kt * 4096 + (ni * 16 + idx) * 32 + kgx);    \
    _Pragma("unroll") for (int mi = 0; mi < 4; ++mi)                        \
        _Pragma("unroll") for (int ni = 0; ni < 4; ++ni) acc[mi][ni] =      \
            __builtin_amdgcn_mfma_f32_16x16x32_bf16(af[mi], bf[ni],         \
                                                    acc[mi][ni], 0, 0, 0);  \
  }

  // ---- GEMM1: C1 = xconv @ wq^T -> sC (bf16) + row sumsq -> ssL ----------
  {
    f32x4 acc[4][4] = {};
    GEMM_LOOP(sX, tq)
#pragma unroll
    for (int mi = 0; mi < 4; ++mi) {
#pragma unroll
      for (int j = 0; j < 4; ++j) {
        const int r = mi * 16 + kg * 4 + j;
        float ps = 0.0f;
#pragma unroll
        for (int ni = 0; ni < 4; ++ni) {
          const float v = acc[mi][ni][j];
          ps += v * v;
          sC[ldsoff(r, cbase + ni * 16 + idx)] = __float2bfloat16(v);
        }
        ps += __shfl_xor(ps, 1, 64);
        ps += __shfl_xor(ps, 2, 64);
        ps += __shfl_xor(ps, 4, 64);
        ps += __shfl_xor(ps, 8, 64);
        if (idx == 0) atomicAdd(&ssL[r], ps);
      }
    }
  }
  __syncthreads();  // sC + ssL complete; sX reads done -> may overwrite

  // ---- GEMM2: G = gelu(sc * (C1 @ w1)) -> sX (bf16) ----------------------
  {
    f32x4 acc[4][4] = {};
    GEMM_LOOP(sC, t1)
#pragma unroll
    for (int mi = 0; mi < 4; ++mi) {
#pragma unroll
      for (int j = 0; j < 4; ++j) {
        const int r = mi * 16 + kg * 4 + j;
        const float sc = 1.0f / fmaxf(sqrtf(ssL[r]), 1e-12f);
#pragma unroll
        for (int ni = 0; ni < 4; ++ni) {
          const float v = acc[mi][ni][j] * sc;
          const float ge = 0.5f * v * (1.0f + erff(v * 0.70710678118654752f));
          sX[ldsoff(r, cbase + ni * 16 + idx)] = __float2bfloat16(ge);
        }
      }
    }
  }
  __syncthreads();  // G complete

  // ---- GEMM3: out = sc*C1 + G @ w2 (f32, row-major) ----------------------
  {
    f32x4 acc[4][4] = {};
    GEMM_LOOP(sX, t2)
#pragma unroll
    for (int mi = 0; mi < 4; ++mi) {
#pragma unroll
      for (int j = 0; j < 4; ++j) {
        const int r = mi * 16 + kg * 4 + j;
        const float sc = 1.0f / fmaxf(sqrtf(ssL[r]), 1e-12f);
#pragma unroll
        for (int ni = 0; ni < 4; ++ni) {
          const int c = cbase + ni * 16 + idx;
          out[(size_t)(r0 + r) * DIM + c] =
              acc[mi][ni][j] + sc * __bfloat162float(sC[ldsoff(r, c)]);
        }
      }
    }
  }
#undef GEMM_LOOP
}

extern "C" void kernel_launch(void* const* d_in, const int* in_sizes, int n_in,
                              void* d_out, int out_size, void* d_ws,
                              size_t ws_size, hipStream_t stream) {
  const float* x = (const float*)d_in[0];
  const float* cw = (const float*)d_in[1];
  const float* cb = (const float*)d_in[2];
  const float* qw = (const float*)d_in[3];
  const float* w1 = (const float*)d_in[4];
  const float* w2 = (const float*)d_in[5];
  float* out = (float*)d_out;

  // ws layout (high-water ~65.6 MB, well under proven-safe 135.79 MB):
  //   [0, 64Mi)          xconv packed bf16
  //   [64Mi, +512K)      wq packed bf16
  //   [+512K, +1M)       w1t packed bf16
  //   [+1M, +1.5M)       w2t packed bf16
  //   [+1.5M, +1.5M+8K)  cwt f32 [4][512]
  char* ws = (char*)d_ws;
  __hip_bfloat16* xconv = (__hip_bfloat16*)ws;
  __hip_bfloat16* wqp = (__hip_bfloat16*)(ws + (size_t)67108864);
  __hip_bfloat16* w1p = wqp + DIM * DIM;
  __hip_bfloat16* w2p = w1p + DIM * DIM;
  float* cwt = (float*)(ws + (size_t)67108864 + 3 * 524288);

  prep_w<<<DIM * DIM / 256, 256, 0, stream>>>(qw, wqp, 0, cw, cwt);
  prep_w<<<DIM * DIM / 256, 256, 0, stream>>>(w1, w1p, 1, nullptr, nullptr);
  prep_w<<<DIM * DIM / 256, 256, 0, stream>>>(w2, w2p, 1, nullptr, nullptr);
  conv_cast_kernel<<<ML * (DIM / 4) / 256, 256, 0, stream>>>(x, cwt, cb, xconv);
  fused_kernel<<<ML / 64, 512, 0, stream>>>(xconv, wqp, w1p, w2p, out);
}